// Round 11
// baseline (73.060 us; speedup 1.0000x reference)
//
#include <hip/hip_runtime.h>
#include <float.h>

#define Bsz 2048
#define Nn  1024
#define Dd  256

typedef __attribute__((ext_vector_type(8))) short bf16x8;
typedef __attribute__((ext_vector_type(4))) float f32x4;
typedef unsigned long long u64;

union b8u4 { bf16x8 v; uint4 u; };

__device__ __forceinline__ void som_params(const int* __restrict__ step,
                                           const int* __restrict__ total,
                                           float* taxa, float* inv2s2) {
    float frac = (float)(*step) / (float)(*total);
    float e = __expf(-frac);
    *taxa = 0.5f * e;
    float sigma = 16.0f * e;              // SIGMA_INICIAL = 16
    *inv2s2 = 1.0f / (2.0f * sigma * sigma);
}

// sortable-u32 encoding of f32 (monotone), packed with index; min => argmin
// with first-index (lowest n) tie-break, matching jnp.argmin.
__device__ __forceinline__ u64 packsc(float f, int n) {
    unsigned u = __float_as_uint(f);
    u = (u & 0x80000000u) ? ~u : (u | 0x80000000u);
    return ((u64)u << 32) | (unsigned)n;
}

// cheap TRUNCATION hi/lo split of 8 consecutive f32, pair-packed;
// 3-MFMA correction absorbs the larger truncation-lo. returns sum of squares.
__device__ __forceinline__ float split8t(const float* __restrict__ src,
                                         bf16x8* hi, bf16x8* lo) {
    float4 v0 = *(const float4*)src;
    float4 v1 = *(const float4*)(src + 4);
    float f[8] = {v0.x, v0.y, v0.z, v0.w, v1.x, v1.y, v1.z, v1.w};
    float s = 0.f;
    unsigned hp[4], lp[4];
    #pragma unroll
    for (int p = 0; p < 4; ++p) {
        float a = f[2*p], b = f[2*p+1];
        unsigned ua = __float_as_uint(a), ub = __float_as_uint(b);
        unsigned ha = ua & 0xffff0000u, hb = ub & 0xffff0000u;
        float la = a - __uint_as_float(ha);
        float lb = b - __uint_as_float(hb);
        hp[p] = (ua >> 16) | hb;
        lp[p] = (__float_as_uint(la) >> 16) | (__float_as_uint(lb) & 0xffff0000u);
        s = fmaf(a, a, s); s = fmaf(b, b, s);
    }
    b8u4 H, L;
    H.u = make_uint4(hp[0], hp[1], hp[2], hp[3]);
    L.u = make_uint4(lp[0], lp[1], lp[2], lp[3]);
    *hi = H.v; *lo = L.v;
    return s;
}

// ---------------------------------------------------------------------------
// K1 (256 blocks, 256 thr): BMU partials from RAW f32 X,W — in-register
// split+w2; block tile 128b x 64n (wm=b-half, wn=n-half waves);
// packed per-(n-tile,b) min -> ppack.   (validated since R8)
// ---------------------------------------------------------------------------
__global__ __launch_bounds__(256) void bmu_pre(
    const float* __restrict__ X, const float* __restrict__ W,
    u64* __restrict__ ppack)
{
    __shared__ u64 lmin[2][2][64];     // [wm][wn][b_local]

    const int t = threadIdx.x, bid = blockIdx.x;
    const int w = t >> 6, l = t & 63;
    const int lr = l & 15, lg = l >> 4;

    const int wm = w & 1, wn = w >> 1;
    const int b0 = (bid >> 4) * 128 + wm * 64;
    const int n0 = (bid & 15) * 64 + wn * 32;

    f32x4 acc[4][2];
    #pragma unroll
    for (int m = 0; m < 4; ++m)
        #pragma unroll
        for (int n = 0; n < 2; ++n) { f32x4 z = {0.f,0.f,0.f,0.f}; acc[m][n] = z; }
    float w2a[2] = {0.f, 0.f};

    #pragma unroll 2
    for (int kd = 0; kd < Dd; kd += 32) {
        bf16x8 ah[4], al[4], bh[2], bl[2];
        #pragma unroll
        for (int m = 0; m < 4; ++m)
            split8t(&X[(size_t)(b0 + m*16 + lr) * Dd + kd + lg*8], &ah[m], &al[m]);
        #pragma unroll
        for (int nf = 0; nf < 2; ++nf)
            w2a[nf] += split8t(&W[(size_t)(n0 + nf*16 + lr) * Dd + kd + lg*8],
                               &bh[nf], &bl[nf]);
        #pragma unroll
        for (int m = 0; m < 4; ++m)
            #pragma unroll
            for (int nf = 0; nf < 2; ++nf) {
                acc[m][nf] = __builtin_amdgcn_mfma_f32_16x16x32_bf16(ah[m], bh[nf], acc[m][nf], 0, 0, 0);
                acc[m][nf] = __builtin_amdgcn_mfma_f32_16x16x32_bf16(ah[m], bl[nf], acc[m][nf], 0, 0, 0);
                acc[m][nf] = __builtin_amdgcn_mfma_f32_16x16x32_bf16(al[m], bh[nf], acc[m][nf], 0, 0, 0);
            }
    }

    #pragma unroll
    for (int nf = 0; nf < 2; ++nf) {
        w2a[nf] += __shfl_xor(w2a[nf], 16, 64);
        w2a[nf] += __shfl_xor(w2a[nf], 32, 64);
    }
    const int ni0 = n0 + lr, ni1 = n0 + 16 + lr;

    #pragma unroll
    for (int m = 0; m < 4; ++m)
        #pragma unroll
        for (int r = 0; r < 4; ++r) {
            u64 p0 = packsc(w2a[0] - 2.f * acc[m][0][r], ni0);
            u64 p1 = packsc(w2a[1] - 2.f * acc[m][1][r], ni1);
            u64 pm = p1 < p0 ? p1 : p0;
            #pragma unroll
            for (int msk = 1; msk < 16; msk <<= 1) {
                unsigned plo = (unsigned)pm, phi = (unsigned)(pm >> 32);
                plo = __shfl_xor(plo, msk, 64);
                phi = __shfl_xor(phi, msk, 64);
                u64 o = ((u64)phi << 32) | plo;
                if (o < pm) pm = o;
            }
            if (lr == 0) lmin[wm][wn][m*16 + lg*4 + r] = pm;
        }
    __syncthreads();
    if (t < 128) {
        const int bwm = t >> 6, bb = t & 63;
        u64 a = lmin[bwm][0][bb], c = lmin[bwm][1][bb];
        u64 pm = c < a ? c : a;
        const int b = (bid >> 4) * 128 + bwm * 64 + bb;
        ppack[(size_t)(bid & 15) * Bsz + b] = pm;
    }
}

// ---------------------------------------------------------------------------
// K2 (32 blocks = d-slices of 8, 256 thr): final argmin + scatter-sum
// S[g, dslice] in LDS + Ex-contraction:  T[gy][nx][d] = sum_gx Ex[nx,gx]*S.
// block 0 also emits cnt[g].  No global atomics, no zero-init kernel.
// ---------------------------------------------------------------------------
__global__ __launch_bounds__(256) void scatter_t(
    const float* __restrict__ X, const u64* __restrict__ ppack,
    const int* __restrict__ step, const int* __restrict__ total,
    float* __restrict__ T, int* __restrict__ cnt_g)
{
    __shared__ float  S_l[Nn][8];      // 32 KB
    __shared__ float  Ex_l[32][32];    // 4 KB
    __shared__ ushort bidx_l[Bsz];     // 4 KB
    __shared__ int    cnt_l[Nn];       // 4 KB

    const int t = threadIdx.x, bid = blockIdx.x;
    const int d0 = bid * 8;

    float taxa, inv2s2;
    som_params(step, total, &taxa, &inv2s2);

    // zero S_l and cnt_l; build Ex table
    #pragma unroll
    for (int i = 0; i < 32; ++i) ((float*)S_l)[t + 256*i] = 0.f;
    #pragma unroll
    for (int i = 0; i < 4; ++i) cnt_l[t + 256*i] = 0;
    #pragma unroll
    for (int i = 0; i < 4; ++i) {
        int idx = t + 256*i;
        int nx = idx >> 5, gx = idx & 31;
        float d = (float)(nx - gx);
        Ex_l[nx][gx] = __expf(-(d*d) * inv2s2);
    }
    __syncthreads();

    // phase 1: final argmin per b (coalesced), counts
    #pragma unroll
    for (int i = 0; i < 8; ++i) {
        const int b = t + 256*i;
        u64 pm = ppack[b];
        #pragma unroll
        for (int g = 1; g < 16; ++g) {
            u64 c = ppack[(size_t)g * Bsz + b];
            if (c < pm) pm = c;
        }
        ushort gi = (ushort)(pm & 0xffffu);
        bidx_l[b] = gi;
        atomicAdd(&cnt_l[gi], 1);
    }
    __syncthreads();

    if (bid == 0) {
        #pragma unroll
        for (int i = 0; i < 4; ++i) cnt_g[t + 256*i] = cnt_l[t + 256*i];
    }

    // phase 2: scatter-sum X rows into S_l (this block's 8 d columns)
    {
        const int dt = t & 7, bg = t >> 3;   // 32 b-groups of 64
        #pragma unroll 8
        for (int i = 0; i < 64; ++i) {
            const int b = bg * 64 + i;
            const int g = bidx_l[b];
            atomicAdd(&S_l[g][dt], X[(size_t)b * Dd + d0 + dt]);
        }
    }
    __syncthreads();

    // phase 3: T[gy][nx][d0+dt] = sum_gx Ex[nx,gx] * S_l[gy*32+gx][dt]
    {
        const int gyg = t >> 5;              // 0..7 -> 4 gy each
        const int nxc = (t >> 3) & 3;        // 8 nx each
        const int dt  = t & 7;
        #pragma unroll
        for (int gyl = 0; gyl < 4; ++gyl) {
            const int gy = gyg * 4 + gyl;
            float a8[8] = {0,0,0,0,0,0,0,0};
            #pragma unroll
            for (int gx = 0; gx < 32; ++gx) {
                float s = S_l[gy*32 + gx][dt];
                #pragma unroll
                for (int j = 0; j < 8; ++j)
                    a8[j] = fmaf(Ex_l[nxc*8 + j][gx], s, a8[j]);
            }
            #pragma unroll
            for (int j = 0; j < 8; ++j)
                T[(size_t)(gy*32 + nxc*8 + j) * Dd + d0 + dt] = a8[j];
        }
    }
}

// ---------------------------------------------------------------------------
// K3 (256 blocks, 256 thr): out[n][d] = W + taxa*(acc - hsum*W)/B with
// acc[n][d] = sum_gy Ey[ny,gy]*T[gy][nx][d];  hsum from cnt (exact regroup).
// block = 4 consecutive n (same ny); thread = one d column.
// ---------------------------------------------------------------------------
__global__ __launch_bounds__(256) void finish(
    const float* __restrict__ T, const int* __restrict__ cnt_g,
    const float* __restrict__ W, const int* __restrict__ step,
    const int* __restrict__ total, float* __restrict__ out)
{
    __shared__ float Exc_l[4][32];
    __shared__ float hsum_l[4];

    const int t = threadIdx.x, bid = blockIdx.x;
    const int n0 = bid * 4;
    const int ny = n0 >> 5;
    const int nxb = n0 & 31;

    float taxa, inv2s2;
    som_params(step, total, &taxa, &inv2s2);
    const float invB = 1.0f / 2048.0f;

    // Exc[nxl][gy] = sum_gx Ex[nx,gx]*cnt[gy*32+gx]
    if (t < 128) {
        const int nxl = t >> 5, gy = t & 31;
        const int nx = nxb + nxl;
        float s = 0.f;
        #pragma unroll
        for (int gx = 0; gx < 32; ++gx) {
            float d = (float)(nx - gx);
            s = fmaf(__expf(-(d*d) * inv2s2), (float)cnt_g[gy*32 + gx], s);
        }
        Exc_l[nxl][gy] = s;
    }
    __syncthreads();
    if (t < 4) {
        float s = 0.f;
        #pragma unroll
        for (int gy = 0; gy < 32; ++gy) {
            float d = (float)(ny - gy);
            s = fmaf(__expf(-(d*d) * inv2s2), Exc_l[t][gy], s);
        }
        hsum_l[t] = s;
    }
    __syncthreads();

    // hoist Ey row (wave-uniform)
    float ey[32];
    #pragma unroll
    for (int gy = 0; gy < 32; ++gy) {
        float d = (float)(ny - gy);
        ey[gy] = __expf(-(d*d) * inv2s2);
    }

    #pragma unroll
    for (int nl = 0; nl < 4; ++nl) {
        const int n = n0 + nl;
        const int nx = nxb + nl;
        float acc = 0.f;
        #pragma unroll
        for (int gy = 0; gy < 32; ++gy)
            acc = fmaf(ey[gy], T[(size_t)(gy*32 + nx) * Dd + t], acc);
        const float wv = W[(size_t)n * Dd + t];
        out[(size_t)n * Dd + t] = wv + taxa * (acc - hsum_l[nl] * wv) * invB;
    }
}

// ---------------------------------------------------------------------------
extern "C" void kernel_launch(void* const* d_in, const int* in_sizes, int n_in,
                              void* d_out, int out_size, void* d_ws, size_t ws_size,
                              hipStream_t stream)
{
    const float* X    = (const float*)d_in[0];
    const float* W    = (const float*)d_in[1];
    const int* step   = (const int*)d_in[3];
    const int* total  = (const int*)d_in[4];
    float* out = (float*)d_out;

    // workspace (~1.27 MB): ppack u64[16][2048] | T f32[32][32][256] | cnt int[1024]
    char* p = (char*)d_ws;
    u64*   ppack = (u64*)p;   p += 262144;
    float* T     = (float*)p; p += 1048576;
    int*   cnt   = (int*)p;   p += 4096;

    bmu_pre  <<<256, 256, 0, stream>>>(X, W, ppack);
    scatter_t<<<32, 256, 0, stream>>>(X, ppack, step, total, T, cnt);
    finish   <<<256, 256, 0, stream>>>(T, cnt, W, step, total, out);
}

// Round 12
// 40.176 us; speedup vs baseline: 1.8185x; 1.8185x over previous
//
#include <hip/hip_runtime.h>
#include <float.h>

#define Bsz 2048
#define Nn  1024
#define Dd  256

typedef __attribute__((ext_vector_type(8))) short bf16x8;
typedef __attribute__((ext_vector_type(4))) float f32x4;
typedef unsigned long long u64;

union b8u4 { bf16x8 v; uint4 u; };

__device__ __forceinline__ void som_params(const int* __restrict__ step,
                                           const int* __restrict__ total,
                                           float* taxa, float* inv2s2) {
    float frac = (float)(*step) / (float)(*total);
    float e = __expf(-frac);
    *taxa = 0.5f * e;
    float sigma = 16.0f * e;              // SIGMA_INICIAL = 16
    *inv2s2 = 1.0f / (2.0f * sigma * sigma);
}

// sortable-u32 encoding of f32 (monotone), packed with index; min => argmin
// with first-index (lowest n) tie-break, matching jnp.argmin.
__device__ __forceinline__ u64 packsc(float f, int n) {
    unsigned u = __float_as_uint(f);
    u = (u & 0x80000000u) ? ~u : (u | 0x80000000u);
    return ((u64)u << 32) | (unsigned)n;
}

// cheap TRUNCATION hi/lo split of 8 consecutive f32, pair-packed;
// 3-MFMA correction absorbs the larger truncation-lo. returns sum of squares.
__device__ __forceinline__ float split8t(const float* __restrict__ src,
                                         bf16x8* hi, bf16x8* lo) {
    float4 v0 = *(const float4*)src;
    float4 v1 = *(const float4*)(src + 4);
    float f[8] = {v0.x, v0.y, v0.z, v0.w, v1.x, v1.y, v1.z, v1.w};
    float s = 0.f;
    unsigned hp[4], lp[4];
    #pragma unroll
    for (int p = 0; p < 4; ++p) {
        float a = f[2*p], b = f[2*p+1];
        unsigned ua = __float_as_uint(a), ub = __float_as_uint(b);
        unsigned ha = ua & 0xffff0000u, hb = ub & 0xffff0000u;
        float la = a - __uint_as_float(ha);
        float lb = b - __uint_as_float(hb);
        hp[p] = (ua >> 16) | hb;
        lp[p] = (__float_as_uint(la) >> 16) | (__float_as_uint(lb) & 0xffff0000u);
        s = fmaf(a, a, s); s = fmaf(b, b, s);
    }
    b8u4 H, L;
    H.u = make_uint4(hp[0], hp[1], hp[2], hp[3]);
    L.u = make_uint4(lp[0], lp[1], lp[2], lp[3]);
    *hi = H.v; *lo = L.v;
    return s;
}

// ---------------------------------------------------------------------------
// K1 (256 blocks, 256 thr): BMU partials from RAW f32 X,W — in-register
// split+w2; block tile 128b x 64n (wm=b-half, wn=n-half waves);
// packed per-(n-tile,b) min -> ppack.   (unchanged, validated since R8)
// ---------------------------------------------------------------------------
__global__ __launch_bounds__(256) void bmu_pre(
    const float* __restrict__ X, const float* __restrict__ W,
    u64* __restrict__ ppack)
{
    __shared__ u64 lmin[2][2][64];     // [wm][wn][b_local]

    const int t = threadIdx.x, bid = blockIdx.x;
    const int w = t >> 6, l = t & 63;
    const int lr = l & 15, lg = l >> 4;

    const int wm = w & 1, wn = w >> 1;
    const int b0 = (bid >> 4) * 128 + wm * 64;
    const int n0 = (bid & 15) * 64 + wn * 32;

    f32x4 acc[4][2];
    #pragma unroll
    for (int m = 0; m < 4; ++m)
        #pragma unroll
        for (int n = 0; n < 2; ++n) { f32x4 z = {0.f,0.f,0.f,0.f}; acc[m][n] = z; }
    float w2a[2] = {0.f, 0.f};

    #pragma unroll 2
    for (int kd = 0; kd < Dd; kd += 32) {
        bf16x8 ah[4], al[4], bh[2], bl[2];
        #pragma unroll
        for (int m = 0; m < 4; ++m)
            split8t(&X[(size_t)(b0 + m*16 + lr) * Dd + kd + lg*8], &ah[m], &al[m]);
        #pragma unroll
        for (int nf = 0; nf < 2; ++nf)
            w2a[nf] += split8t(&W[(size_t)(n0 + nf*16 + lr) * Dd + kd + lg*8],
                               &bh[nf], &bl[nf]);
        #pragma unroll
        for (int m = 0; m < 4; ++m)
            #pragma unroll
            for (int nf = 0; nf < 2; ++nf) {
                acc[m][nf] = __builtin_amdgcn_mfma_f32_16x16x32_bf16(ah[m], bh[nf], acc[m][nf], 0, 0, 0);
                acc[m][nf] = __builtin_amdgcn_mfma_f32_16x16x32_bf16(ah[m], bl[nf], acc[m][nf], 0, 0, 0);
                acc[m][nf] = __builtin_amdgcn_mfma_f32_16x16x32_bf16(al[m], bh[nf], acc[m][nf], 0, 0, 0);
            }
    }

    #pragma unroll
    for (int nf = 0; nf < 2; ++nf) {
        w2a[nf] += __shfl_xor(w2a[nf], 16, 64);
        w2a[nf] += __shfl_xor(w2a[nf], 32, 64);
    }
    const int ni0 = n0 + lr, ni1 = n0 + 16 + lr;

    #pragma unroll
    for (int m = 0; m < 4; ++m)
        #pragma unroll
        for (int r = 0; r < 4; ++r) {
            u64 p0 = packsc(w2a[0] - 2.f * acc[m][0][r], ni0);
            u64 p1 = packsc(w2a[1] - 2.f * acc[m][1][r], ni1);
            u64 pm = p1 < p0 ? p1 : p0;
            #pragma unroll
            for (int msk = 1; msk < 16; msk <<= 1) {
                unsigned plo = (unsigned)pm, phi = (unsigned)(pm >> 32);
                plo = __shfl_xor(plo, msk, 64);
                phi = __shfl_xor(phi, msk, 64);
                u64 o = ((u64)phi << 32) | plo;
                if (o < pm) pm = o;
            }
            if (lr == 0) lmin[wm][wn][m*16 + lg*4 + r] = pm;
        }
    __syncthreads();
    if (t < 128) {
        const int bwm = t >> 6, bb = t & 63;
        u64 a = lmin[bwm][0][bb], c = lmin[bwm][1][bb];
        u64 pm = c < a ? c : a;
        const int b = (bid >> 4) * 128 + bwm * 64 + bb;
        ppack[(size_t)(bid & 15) * Bsz + b] = pm;
    }
}

// ---------------------------------------------------------------------------
// K2 (256 blocks = 32 gy x 8 d-chunks, 256 thr): gather-by-ownership.
// Each block: final argmin for all b (coalesced) -> keep only b with
// by(b)==gy (deterministic prefix-sum compaction into LDS list) ->
// T[gy*32+nx][d0+dd] = sum_list Ex[nx,bx(b)] * X[b,d0+dd].
// dc==0 blocks also emit cnt_g[gy*32+gx] (int LDS atomics, order-free).
// No float atomics; fully deterministic.
// ---------------------------------------------------------------------------
__global__ __launch_bounds__(256) void scatter_t(
    const float* __restrict__ X, const u64* __restrict__ ppack,
    const int* __restrict__ step, const int* __restrict__ total,
    float* __restrict__ T, int* __restrict__ cnt_g)
{
    __shared__ ushort list[Bsz];       // packed (b<<5)|bx, worst case 2048
    __shared__ float  Ex_l[32][32];
    __shared__ int    psum[256];
    __shared__ int    cnt32[32];

    const int t = threadIdx.x, bid = blockIdx.x;
    const int gy = bid >> 3, dc = bid & 7, d0 = dc * 32;

    float taxa, inv2s2;
    som_params(step, total, &taxa, &inv2s2);

    if (t < 32) cnt32[t] = 0;
    #pragma unroll
    for (int i = 0; i < 4; ++i) {
        int idx = t + 256*i;
        int nx = idx >> 5, gx = idx & 31;
        float d = (float)(nx - gx);
        Ex_l[nx][gx] = __expf(-(d*d) * inv2s2);
    }
    __syncthreads();

    // phase 1: final argmin per b (coalesced); record this-gy matches
    int g8[8];
    int mycnt = 0;
    #pragma unroll
    for (int i = 0; i < 8; ++i) {
        const int b = t + 256*i;
        u64 pm = ppack[b];
        #pragma unroll
        for (int g = 1; g < 16; ++g) {
            u64 c = ppack[(size_t)g * Bsz + b];
            if (c < pm) pm = c;
        }
        g8[i] = (int)(pm & 0xffffu);
        bool m = (g8[i] >> 5) == gy;
        mycnt += m ? 1 : 0;
        if (m && dc == 0) atomicAdd(&cnt32[g8[i] & 31], 1);
    }

    // phase 2: deterministic compaction (Hillis-Steele inclusive scan)
    psum[t] = mycnt;
    __syncthreads();
    #pragma unroll
    for (int off = 1; off < 256; off <<= 1) {
        int v = (t >= off) ? psum[t - off] : 0;
        __syncthreads();
        psum[t] += v;
        __syncthreads();
    }
    const int nmatch = psum[255];
    int pos = psum[t] - mycnt;
    #pragma unroll
    for (int i = 0; i < 8; ++i) {
        const int b = t + 256*i;
        if ((g8[i] >> 5) == gy) list[pos++] = (ushort)((b << 5) | (g8[i] & 31));
    }
    if (dc == 0 && t < 32) cnt_g[gy*32 + t] = cnt32[t];
    __syncthreads();

    // phase 3: accumulate this block's 32nx x 32d tile over the list
    const int nx = t >> 3, dq = t & 7;
    float4 a = make_float4(0.f, 0.f, 0.f, 0.f);
    for (int k = 0; k < nmatch; ++k) {
        const int rec = list[k];
        const int b = rec >> 5, bx = rec & 31;
        const float ex = Ex_l[nx][bx];
        float4 xv = *(const float4*)&X[(size_t)b * Dd + d0 + dq*4];
        a.x = fmaf(ex, xv.x, a.x);
        a.y = fmaf(ex, xv.y, a.y);
        a.z = fmaf(ex, xv.z, a.z);
        a.w = fmaf(ex, xv.w, a.w);
    }
    *(float4*)&T[(size_t)(gy*32 + nx) * Dd + d0 + dq*4] = a;
}

// ---------------------------------------------------------------------------
// K3 (256 blocks, 256 thr): out[n][d] = W + taxa*(acc - hsum*W)/B with
// acc[n][d] = sum_gy Ey[ny,gy]*T[gy][nx][d];  hsum from cnt (exact regroup).
// block = 4 consecutive n (same ny); thread = one d column.  (unchanged)
// ---------------------------------------------------------------------------
__global__ __launch_bounds__(256) void finish(
    const float* __restrict__ T, const int* __restrict__ cnt_g,
    const float* __restrict__ W, const int* __restrict__ step,
    const int* __restrict__ total, float* __restrict__ out)
{
    __shared__ float Exc_l[4][32];
    __shared__ float hsum_l[4];

    const int t = threadIdx.x, bid = blockIdx.x;
    const int n0 = bid * 4;
    const int ny = n0 >> 5;
    const int nxb = n0 & 31;

    float taxa, inv2s2;
    som_params(step, total, &taxa, &inv2s2);
    const float invB = 1.0f / 2048.0f;

    // Exc[nxl][gy] = sum_gx Ex[nx,gx]*cnt[gy*32+gx]
    if (t < 128) {
        const int nxl = t >> 5, gy = t & 31;
        const int nx = nxb + nxl;
        float s = 0.f;
        #pragma unroll
        for (int gx = 0; gx < 32; ++gx) {
            float d = (float)(nx - gx);
            s = fmaf(__expf(-(d*d) * inv2s2), (float)cnt_g[gy*32 + gx], s);
        }
        Exc_l[nxl][gy] = s;
    }
    __syncthreads();
    if (t < 4) {
        float s = 0.f;
        #pragma unroll
        for (int gy = 0; gy < 32; ++gy) {
            float d = (float)(ny - gy);
            s = fmaf(__expf(-(d*d) * inv2s2), Exc_l[t][gy], s);
        }
        hsum_l[t] = s;
    }
    __syncthreads();

    // hoist Ey row (wave-uniform)
    float ey[32];
    #pragma unroll
    for (int gy = 0; gy < 32; ++gy) {
        float d = (float)(ny - gy);
        ey[gy] = __expf(-(d*d) * inv2s2);
    }

    #pragma unroll
    for (int nl = 0; nl < 4; ++nl) {
        const int n = n0 + nl;
        const int nx = nxb + nl;
        float acc = 0.f;
        #pragma unroll
        for (int gy = 0; gy < 32; ++gy)
            acc = fmaf(ey[gy], T[(size_t)(gy*32 + nx) * Dd + t], acc);
        const float wv = W[(size_t)n * Dd + t];
        out[(size_t)n * Dd + t] = wv + taxa * (acc - hsum_l[nl] * wv) * invB;
    }
}

// ---------------------------------------------------------------------------
extern "C" void kernel_launch(void* const* d_in, const int* in_sizes, int n_in,
                              void* d_out, int out_size, void* d_ws, size_t ws_size,
                              hipStream_t stream)
{
    const float* X    = (const float*)d_in[0];
    const float* W    = (const float*)d_in[1];
    const int* step   = (const int*)d_in[3];
    const int* total  = (const int*)d_in[4];
    float* out = (float*)d_out;

    // workspace (~1.27 MB): ppack u64[16][2048] | T f32[32][32][256] | cnt int[1024]
    char* p = (char*)d_ws;
    u64*   ppack = (u64*)p;   p += 262144;
    float* T     = (float*)p; p += 1048576;
    int*   cnt   = (int*)p;   p += 4096;

    bmu_pre  <<<256, 256, 0, stream>>>(X, W, ppack);
    scatter_t<<<256, 256, 0, stream>>>(X, ppack, step, total, T, cnt);
    finish   <<<256, 256, 0, stream>>>(T, cnt, W, step, total, out);
}